// Round 1
// baseline (435.102 us; speedup 1.0000x reference)
//
#include <hip/hip_runtime.h>
#include <hip/hip_bf16.h>
#include <stdint.h>

#define HW 16384
#define BATCH 32

typedef __bf16 bf16_t;
typedef bf16_t bf16x8 __attribute__((ext_vector_type(8)));
typedef float f32x4 __attribute__((ext_vector_type(4)));

// tanh-form GELU: gelu(x) = x * sigmoid(2*0.79788456*(x + 0.044715 x^3))
// max abs deviation from exact erf-GELU ~3e-4, far under the 9.3e-2 threshold.
__device__ __forceinline__ float gelu_f(float x) {
    float u = x * (1.0f + 0.044715f * x * x);
    return x / (1.0f + __expf(-1.5957691216057308f * u));
}

__device__ __forceinline__ bf16x8 cvt8(float4 lo, float4 hi) {
    bf16x8 r;
    r[0] = (bf16_t)lo.x; r[1] = (bf16_t)lo.y; r[2] = (bf16_t)lo.z; r[3] = (bf16_t)lo.w;
    r[4] = (bf16_t)hi.x; r[5] = (bf16_t)hi.y; r[6] = (bf16_t)hi.z; r[7] = (bf16_t)hi.w;
    return r;
}

__device__ __forceinline__ uint32_t pk2(float a, float b) {
    union { bf16_t h[2]; uint32_t u; } z;
    z.h[0] = (bf16_t)a; z.h[1] = (bf16_t)b;
    return z.u;
}

// ---------------------------------------------------------------------------
// Kernel 1: features = gelu(fe_w @ x + fe_b), write bf16 pixel-major [b][p][c],
// and accumulate gf_sum[b][c] = sum over pixels of features (fp32 atomics).
// Grid: 32 samples * 64 stripes of 256 px. Block 256 thr (4 waves, 64 px/wave).
// ---------------------------------------------------------------------------
__global__ __launch_bounds__(256, 4)
void k1_feat(const float* __restrict__ x, const float* __restrict__ fe_w,
             const float* __restrict__ fe_b, bf16_t* __restrict__ feat,
             float* __restrict__ gf_sum) {
    // x tile [64 ch][256 px] as bf16, pitch 258 => k-groups offset by 8 banks
    __shared__ bf16_t xs[64 * 258];
    __shared__ float gf4[4][64];

    int tid = threadIdx.x;
    int lane = tid & 63;
    int wid = tid >> 6;
    int r16 = lane & 15;
    int g = lane >> 4;            // quad id 0..3
    int b = blockIdx.x >> 6;      // sample
    int stripe = blockIdx.x & 63;
    int p0 = stripe * 256;

    // A fragments: fe_w[o][c], M=outch, K=cin. lane: m=r16, k=g*8+j (+kh*32)
    bf16x8 A[4][2];
    f32x4 bias[4];
#pragma unroll
    for (int ot = 0; ot < 4; ++ot) {
#pragma unroll
        for (int kh = 0; kh < 2; ++kh) {
            const float4* wp = (const float4*)(fe_w + (ot * 16 + r16) * 64 + kh * 32 + g * 8);
            A[ot][kh] = cvt8(wp[0], wp[1]);
        }
#pragma unroll
        for (int r = 0; r < 4; ++r) bias[ot][r] = fe_b[ot * 16 + g * 4 + r];
    }

    // stage x -> LDS bf16 [c][p]; coalesced float4 global reads
    uint32_t* xsw = (uint32_t*)xs;
#pragma unroll
    for (int i = 0; i < 16; ++i) {
        int lid = i * 256 + tid;
        int c = lid >> 6;
        int pc = lid & 63;
        float4 v = ((const float4*)(x + (size_t)(b * 64 + c) * HW + p0))[pc];
        int widx = c * 129 + pc * 2;   // uint index of element (c*258 + 4*pc)
        xsw[widx] = pk2(v.x, v.y);
        xsw[widx + 1] = pk2(v.z, v.w);
    }
    __syncthreads();

    float gfp[4][4] = {};
    bf16_t* featb = feat + (size_t)b * HW * 64;

#pragma unroll
    for (int t = 0; t < 4; ++t) {
        int pl = (wid * 4 + t) * 16 + r16;   // local pixel [0,256)
        bf16x8 B0, B1;
#pragma unroll
        for (int j = 0; j < 8; ++j) {
            B0[j] = xs[(g * 8 + j) * 258 + pl];
            B1[j] = xs[(32 + g * 8 + j) * 258 + pl];
        }
        int pg = p0 + pl;
#pragma unroll
        for (int ot = 0; ot < 4; ++ot) {
            f32x4 y = {0.f, 0.f, 0.f, 0.f};
            y = __builtin_amdgcn_mfma_f32_16x16x32_bf16(A[ot][0], B0, y, 0, 0, 0);
            y = __builtin_amdgcn_mfma_f32_16x16x32_bf16(A[ot][1], B1, y, 0, 0, 0);
            float vr[4];
#pragma unroll
            for (int r = 0; r < 4; ++r) {
                float v = gelu_f(y[r] + bias[ot][r]);
                gfp[ot][r] += v;
                vr[r] = v;
            }
            uint2 st;
            st.x = pk2(vr[0], vr[1]);
            st.y = pk2(vr[2], vr[3]);
            *(uint2*)(featb + (size_t)pg * 64 + ot * 16 + g * 4) = st;
        }
    }

    // reduce gf over the 16 pixel-lanes of each quad, then across waves
#pragma unroll
    for (int ot = 0; ot < 4; ++ot) {
#pragma unroll
        for (int r = 0; r < 4; ++r) {
            float v = gfp[ot][r];
            v += __shfl_xor(v, 1);
            v += __shfl_xor(v, 2);
            v += __shfl_xor(v, 4);
            v += __shfl_xor(v, 8);
            if (r16 == 0) gf4[wid][ot * 16 + g * 4 + r] = v;
        }
    }
    __syncthreads();
    if (tid < 64) {
        float s = gf4[0][tid] + gf4[1][tid] + gf4[2][tid] + gf4[3][tid];
        atomicAdd(gf_sum + b * 64 + tid, s);
    }
}

// ---------------------------------------------------------------------------
// Kernel 2: gating MLP (exact fp32), one block. Writes per-sample top-2
// expert indices and softmax(temp=2) weights.
// ---------------------------------------------------------------------------
__global__ __launch_bounds__(256)
void k2_gate(const float* __restrict__ gf_sum,
             const float* __restrict__ g1_w, const float* __restrict__ g1_b,
             const float* __restrict__ bn1_g, const float* __restrict__ bn1_b,
             const float* __restrict__ ca1_w, const float* __restrict__ ca1_b,
             const float* __restrict__ ca2_w, const float* __restrict__ ca2_b,
             const float* __restrict__ g2_w, const float* __restrict__ g2_b,
             const float* __restrict__ bn2_g, const float* __restrict__ bn2_b,
             const float* __restrict__ g3_w, const float* __restrict__ g3_b,
             int* __restrict__ gidx, float* __restrict__ gw) {
    __shared__ float gf[32 * 64];
    __shared__ float h1[32 * 128];
    __shared__ float a1[32 * 8];
    __shared__ float hh[32 * 64];
    __shared__ float sc[32 * 8];
    const float R1 = 0.99999500003749969f;   // 1/sqrt(1+1e-5)
    int tid = threadIdx.x;

    for (int i = tid; i < 2048; i += 256) gf[i] = gf_sum[i] * (1.0f / 16384.0f);
    __syncthreads();

    for (int e = tid; e < 4096; e += 256) {
        int b = e >> 7, j = e & 127;
        float s = g1_b[j];
        for (int c = 0; c < 64; ++c) s += gf[b * 64 + c] * g1_w[j * 64 + c];
        s = s * (bn1_g[j] * R1) + bn1_b[j];
        h1[e] = gelu_f(s);
    }
    __syncthreads();
    {
        int b = tid >> 3, j = tid & 7;
        float s = ca1_b[j];
        for (int c = 0; c < 128; ++c) s += h1[b * 128 + c] * ca1_w[j * 128 + c];
        a1[tid] = gelu_f(s);
    }
    __syncthreads();
    for (int e = tid; e < 4096; e += 256) {
        int b = e >> 7, j = e & 127;
        float s = ca2_b[j];
        for (int r = 0; r < 8; ++r) s += a1[b * 8 + r] * ca2_w[j * 8 + r];
        h1[e] = h1[e] / (1.0f + __expf(-2.0f * s));  // * sigmoid(2*att)
    }
    __syncthreads();
    for (int e = tid; e < 2048; e += 256) {
        int b = e >> 6, j = e & 63;
        float s = g2_b[j];
        for (int c = 0; c < 128; ++c) s += h1[b * 128 + c] * g2_w[j * 128 + c];
        s = s * (bn2_g[j] * R1) + bn2_b[j];
        hh[e] = gelu_f(s);
    }
    __syncthreads();
    {
        int b = tid >> 3, j = tid & 7;
        float s = g3_b[j];
        for (int c = 0; c < 64; ++c) s += hh[b * 64 + c] * g3_w[j * 64 + c];
        sc[tid] = s;
    }
    __syncthreads();
    if (tid < 32) {
        int b = tid;
        float v0 = -1e30f, v1 = -1e30f;
        int i0 = 0, i1 = 0;
        for (int e = 0; e < 8; ++e) {
            float s = sc[b * 8 + e];
            if (s > v0) { v1 = v0; i1 = i0; v0 = s; i0 = e; }
            else if (s > v1) { v1 = s; i1 = e; }
        }
        float t = __expf(0.5f * (v1 - v0));   // softmax(vals/2), v0 is max
        float den = 1.0f + t;
        gidx[b * 2] = i0; gidx[b * 2 + 1] = i1;
        gw[b * 2] = 1.0f / den; gw[b * 2 + 1] = t / den;
    }
}

// ---------------------------------------------------------------------------
// Kernel 3: out = 0.5*(gelu(s0)+gelu(s1)) + w0*gelu(e[i0]) + w1*gelu(e[i1]).
// Features read pixel-major bf16 straight from global as B fragments (no LDS).
// All 4 weight mats (stacked 256x64) live in registers as A fragments.
// Grid: 32 samples * 16 stripes of 1024 px. Block 256 thr, 256 px/wave.
// ---------------------------------------------------------------------------
__global__ __launch_bounds__(256, 2)
void k3_out(const bf16_t* __restrict__ feat,
            const float* __restrict__ s_w, const float* __restrict__ s_b,
            const float* __restrict__ e_w, const float* __restrict__ e_b,
            const int* __restrict__ gidx, const float* __restrict__ gw,
            float* __restrict__ out) {
    int tid = threadIdx.x;
    int lane = tid & 63, wid = tid >> 6;
    int r16 = lane & 15, g = lane >> 4;
    int b = blockIdx.x >> 4;
    int stripe = blockIdx.x & 15;

    int i0 = gidx[2 * b], i1 = gidx[2 * b + 1];
    float coef[4] = {0.5f, 0.5f, gw[2 * b], gw[2 * b + 1]};
    const float* Wm[4] = {s_w, s_w + 4096, e_w + (size_t)i0 * 4096, e_w + (size_t)i1 * 4096};
    const float* Bm[4] = {s_b, s_b + 64, e_b + i0 * 64, e_b + i1 * 64};

    bf16x8 A[4][4][2];
    f32x4 biasr[4][4];
#pragma unroll
    for (int m = 0; m < 4; ++m) {
#pragma unroll
        for (int ot = 0; ot < 4; ++ot) {
#pragma unroll
            for (int kh = 0; kh < 2; ++kh) {
                const float4* wp = (const float4*)(Wm[m] + (ot * 16 + r16) * 64 + kh * 32 + g * 8);
                A[m][ot][kh] = cvt8(wp[0], wp[1]);
            }
#pragma unroll
            for (int r = 0; r < 4; ++r) biasr[m][ot][r] = Bm[m][ot * 16 + g * 4 + r];
        }
    }

    const uint4* fb = (const uint4*)(feat + (size_t)b * HW * 64);
    float* outb = out + (size_t)b * 64 * HW;
    int p0w = stripe * 1024 + wid * 256;

    for (int t = 0; t < 16; ++t) {
        int p = p0w + t * 16 + r16;
        uint4 u0 = fb[p * 8 + g];
        uint4 u1 = fb[p * 8 + 4 + g];
        bf16x8 B0 = __builtin_bit_cast(bf16x8, u0);
        bf16x8 B1 = __builtin_bit_cast(bf16x8, u1);
#pragma unroll
        for (int ot = 0; ot < 4; ++ot) {
            f32x4 acc = {0.f, 0.f, 0.f, 0.f};
#pragma unroll
            for (int m = 0; m < 4; ++m) {
                f32x4 y = {0.f, 0.f, 0.f, 0.f};
                y = __builtin_amdgcn_mfma_f32_16x16x32_bf16(A[m][ot][0], B0, y, 0, 0, 0);
                y = __builtin_amdgcn_mfma_f32_16x16x32_bf16(A[m][ot][1], B1, y, 0, 0, 0);
#pragma unroll
                for (int r = 0; r < 4; ++r)
                    acc[r] += coef[m] * gelu_f(y[r] + biasr[m][ot][r]);
            }
            int obase = ot * 16 + g * 4;
#pragma unroll
            for (int r = 0; r < 4; ++r)
                outb[(size_t)(obase + r) * HW + p] = acc[r];
        }
    }
}

extern "C" void kernel_launch(void* const* d_in, const int* in_sizes, int n_in,
                              void* d_out, int out_size, void* d_ws, size_t ws_size,
                              hipStream_t stream) {
    const float* x     = (const float*)d_in[0];
    const float* fe_w  = (const float*)d_in[1];
    const float* fe_b  = (const float*)d_in[2];
    const float* s_w   = (const float*)d_in[3];
    const float* s_b   = (const float*)d_in[4];
    const float* e_w   = (const float*)d_in[5];
    const float* e_b   = (const float*)d_in[6];
    const float* g1_w  = (const float*)d_in[7];
    const float* g1_b  = (const float*)d_in[8];
    const float* bn1_g = (const float*)d_in[9];
    const float* bn1_b = (const float*)d_in[10];
    const float* ca1_w = (const float*)d_in[11];
    const float* ca1_b = (const float*)d_in[12];
    const float* ca2_w = (const float*)d_in[13];
    const float* ca2_b = (const float*)d_in[14];
    const float* g2_w  = (const float*)d_in[15];
    const float* g2_b  = (const float*)d_in[16];
    const float* bn2_g = (const float*)d_in[17];
    const float* bn2_b = (const float*)d_in[18];
    const float* g3_w  = (const float*)d_in[19];
    const float* g3_b  = (const float*)d_in[20];
    float* out = (float*)d_out;

    char* wsb = (char*)d_ws;
    bf16_t* feat  = (bf16_t*)wsb;                          // 64 MiB bf16 features
    float* gf_sum = (float*)(wsb + (size_t)67108864);      // 8 KiB
    int* gidx     = (int*)(wsb + 67108864 + 8192);         // 256 B
    float* gwts   = (float*)(wsb + 67108864 + 8192 + 256); // 256 B

    hipMemsetAsync(gf_sum, 0, 32 * 64 * sizeof(float), stream);
    k1_feat<<<2048, 256, 0, stream>>>(x, fe_w, fe_b, feat, gf_sum);
    k2_gate<<<1, 256, 0, stream>>>(gf_sum, g1_w, g1_b, bn1_g, bn1_b, ca1_w, ca1_b,
                                   ca2_w, ca2_b, g2_w, g2_b, bn2_g, bn2_b, g3_w, g3_b,
                                   gidx, gwts);
    k3_out<<<512, 256, 0, stream>>>(feat, s_w, s_b, e_w, e_b, gidx, gwts, out);
}

// Round 2
// 372.042 us; speedup vs baseline: 1.1695x; 1.1695x over previous
//
#include <hip/hip_runtime.h>
#include <hip/hip_bf16.h>
#include <stdint.h>

#define HW 16384
#define BATCH 32

typedef __bf16 bf16_t;
typedef bf16_t bf16x8 __attribute__((ext_vector_type(8)));
typedef float f32x4 __attribute__((ext_vector_type(4)));

// tanh-form GELU via hw exp2 + hw rcp (no fp32 div sequence):
// gelu(x) = x * sigmoid(1.5957691*(x + 0.044715 x^3))
// 1.5957691216 * log2(e) = 2.3022083
__device__ __forceinline__ float gelu_f(float x) {
    float t = x * fmaf(x * x, 0.044715f, 1.0f);
    float e = __builtin_amdgcn_exp2f(-2.3022083f * t);
    return x * __builtin_amdgcn_rcpf(1.0f + e);
}

__device__ __forceinline__ uint32_t pk2(float a, float b) {
    union { bf16_t h[2]; uint32_t u; } z;
    z.h[0] = (bf16_t)a; z.h[1] = (bf16_t)b;
    return z.u;
}

// ---------------------------------------------------------------------------
// Kernel 0: pre-convert all weight matrices to bf16 in A-fragment lane order.
// Matrix index m: 0=fe_w, 1..2=s_w, 3..10=e_w. Element layout:
//   wbf[ ((m*4+ot)*2+kh)*512 + lane*8 + j ] = W[ot*16 + (lane&15)][kh*32 + (lane>>4)*8 + j]
// Grid: 88 blocks (= 11*4*2) x 64 threads.
// ---------------------------------------------------------------------------
__global__ __launch_bounds__(64)
void k0_conv(const float* __restrict__ fe_w, const float* __restrict__ s_w,
             const float* __restrict__ e_w, bf16_t* __restrict__ wbf) {
    int blk = blockIdx.x;
    int m = blk >> 3;
    int ot = (blk >> 1) & 3;
    int kh = blk & 1;
    int lane = threadIdx.x;
    int r16 = lane & 15, g = lane >> 4;

    const float* W;
    if (m == 0) W = fe_w;
    else if (m <= 2) W = s_w + (size_t)(m - 1) * 4096;
    else W = e_w + (size_t)(m - 3) * 4096;

    const float* src = W + (ot * 16 + r16) * 64 + kh * 32 + g * 8;
    float4 lo = ((const float4*)src)[0];
    float4 hi = ((const float4*)src)[1];
    bf16x8 r;
    r[0] = (bf16_t)lo.x; r[1] = (bf16_t)lo.y; r[2] = (bf16_t)lo.z; r[3] = (bf16_t)lo.w;
    r[4] = (bf16_t)hi.x; r[5] = (bf16_t)hi.y; r[6] = (bf16_t)hi.z; r[7] = (bf16_t)hi.w;
    *(bf16x8*)(wbf + (size_t)blk * 512 + lane * 8) = r;
}

// ---------------------------------------------------------------------------
// Kernel 1: features = gelu(fe_w @ x + fe_b), write bf16 pixel-major [b][p][c],
// accumulate gf_sum[b][c]. Grid: 32 samples * 64 stripes of 256 px, 256 thr.
// ---------------------------------------------------------------------------
__global__ __launch_bounds__(256, 4)
void k1_feat(const float* __restrict__ x, const bf16_t* __restrict__ wbf,
             const float* __restrict__ fe_b, bf16_t* __restrict__ feat,
             float* __restrict__ gf_sum) {
    __shared__ bf16_t xs[64 * 258];
    __shared__ float gf4[4][64];

    int tid = threadIdx.x;
    int lane = tid & 63;
    int wid = tid >> 6;
    int r16 = lane & 15;
    int g = lane >> 4;
    int b = blockIdx.x >> 6;
    int stripe = blockIdx.x & 63;
    int p0 = stripe * 256;

    // A fragments straight from pre-converted bf16 (coalesced dwordx4, no cvt)
    bf16x8 A[4][2];
    f32x4 bias[4];
#pragma unroll
    for (int ot = 0; ot < 4; ++ot) {
#pragma unroll
        for (int kh = 0; kh < 2; ++kh)
            A[ot][kh] = *(const bf16x8*)(wbf + (size_t)((0 * 4 + ot) * 2 + kh) * 512 + lane * 8);
#pragma unroll
        for (int r = 0; r < 4; ++r) bias[ot][r] = fe_b[ot * 16 + g * 4 + r];
    }

    // stage x -> LDS bf16 [c][p], pitch 258 (conflict-free for both phases)
    uint32_t* xsw = (uint32_t*)xs;
#pragma unroll
    for (int i = 0; i < 16; ++i) {
        int lid = i * 256 + tid;
        int c = lid >> 6;
        int pc = lid & 63;
        float4 v = ((const float4*)(x + (size_t)(b * 64 + c) * HW + p0))[pc];
        int widx = c * 129 + pc * 2;
        xsw[widx] = pk2(v.x, v.y);
        xsw[widx + 1] = pk2(v.z, v.w);
    }
    __syncthreads();

    float gfp[4][4] = {};
    bf16_t* featb = feat + (size_t)b * HW * 64;

#pragma unroll
    for (int t = 0; t < 4; ++t) {
        int pl = (wid * 4 + t) * 16 + r16;
        bf16x8 B0, B1;
#pragma unroll
        for (int j = 0; j < 8; ++j) {
            B0[j] = xs[(g * 8 + j) * 258 + pl];
            B1[j] = xs[(32 + g * 8 + j) * 258 + pl];
        }
        int pg = p0 + pl;
#pragma unroll
        for (int ot = 0; ot < 4; ++ot) {
            f32x4 y = {0.f, 0.f, 0.f, 0.f};
            y = __builtin_amdgcn_mfma_f32_16x16x32_bf16(A[ot][0], B0, y, 0, 0, 0);
            y = __builtin_amdgcn_mfma_f32_16x16x32_bf16(A[ot][1], B1, y, 0, 0, 0);
            float vr[4];
#pragma unroll
            for (int r = 0; r < 4; ++r) {
                float v = gelu_f(y[r] + bias[ot][r]);
                gfp[ot][r] += v;
                vr[r] = v;
            }
            uint2 st;
            st.x = pk2(vr[0], vr[1]);
            st.y = pk2(vr[2], vr[3]);
            *(uint2*)(featb + (size_t)pg * 64 + ot * 16 + g * 4) = st;
        }
    }

#pragma unroll
    for (int ot = 0; ot < 4; ++ot) {
#pragma unroll
        for (int r = 0; r < 4; ++r) {
            float v = gfp[ot][r];
            v += __shfl_xor(v, 1);
            v += __shfl_xor(v, 2);
            v += __shfl_xor(v, 4);
            v += __shfl_xor(v, 8);
            if (r16 == 0) gf4[wid][ot * 16 + g * 4 + r] = v;
        }
    }
    __syncthreads();
    if (tid < 64) {
        float s = gf4[0][tid] + gf4[1][tid] + gf4[2][tid] + gf4[3][tid];
        atomicAdd(gf_sum + b * 64 + tid, s);
    }
}

// ---------------------------------------------------------------------------
// Kernel 2: gating MLP (exact fp32), one block.
// ---------------------------------------------------------------------------
__global__ __launch_bounds__(256)
void k2_gate(const float* __restrict__ gf_sum,
             const float* __restrict__ g1_w, const float* __restrict__ g1_b,
             const float* __restrict__ bn1_g, const float* __restrict__ bn1_b,
             const float* __restrict__ ca1_w, const float* __restrict__ ca1_b,
             const float* __restrict__ ca2_w, const float* __restrict__ ca2_b,
             const float* __restrict__ g2_w, const float* __restrict__ g2_b,
             const float* __restrict__ bn2_g, const float* __restrict__ bn2_b,
             const float* __restrict__ g3_w, const float* __restrict__ g3_b,
             int* __restrict__ gidx, float* __restrict__ gw) {
    __shared__ float gf[32 * 64];
    __shared__ float h1[32 * 128];
    __shared__ float a1[32 * 8];
    __shared__ float hh[32 * 64];
    __shared__ float sc[32 * 8];
    const float R1 = 0.99999500003749969f;   // 1/sqrt(1+1e-5)
    int tid = threadIdx.x;

    for (int i = tid; i < 2048; i += 256) gf[i] = gf_sum[i] * (1.0f / 16384.0f);
    __syncthreads();

    for (int e = tid; e < 4096; e += 256) {
        int b = e >> 7, j = e & 127;
        float s = g1_b[j];
        for (int c = 0; c < 64; ++c) s += gf[b * 64 + c] * g1_w[j * 64 + c];
        s = s * (bn1_g[j] * R1) + bn1_b[j];
        h1[e] = gelu_f(s);
    }
    __syncthreads();
    {
        int b = tid >> 3, j = tid & 7;
        float s = ca1_b[j];
        for (int c = 0; c < 128; ++c) s += h1[b * 128 + c] * ca1_w[j * 128 + c];
        a1[tid] = gelu_f(s);
    }
    __syncthreads();
    for (int e = tid; e < 4096; e += 256) {
        int b = e >> 7, j = e & 127;
        float s = ca2_b[j];
        for (int r = 0; r < 8; ++r) s += a1[b * 8 + r] * ca2_w[j * 8 + r];
        // * sigmoid(2*att):  2*log2(e) = 2.8853901
        float e2 = __builtin_amdgcn_exp2f(-2.8853901f * s);
        h1[e] = h1[e] * __builtin_amdgcn_rcpf(1.0f + e2);
    }
    __syncthreads();
    for (int e = tid; e < 2048; e += 256) {
        int b = e >> 6, j = e & 63;
        float s = g2_b[j];
        for (int c = 0; c < 128; ++c) s += h1[b * 128 + c] * g2_w[j * 128 + c];
        s = s * (bn2_g[j] * R1) + bn2_b[j];
        hh[e] = gelu_f(s);
    }
    __syncthreads();
    {
        int b = tid >> 3, j = tid & 7;
        float s = g3_b[j];
        for (int c = 0; c < 64; ++c) s += hh[b * 64 + c] * g3_w[j * 64 + c];
        sc[tid] = s;
    }
    __syncthreads();
    if (tid < 32) {
        int b = tid;
        float v0 = -1e30f, v1 = -1e30f;
        int i0 = 0, i1 = 0;
        for (int e = 0; e < 8; ++e) {
            float s = sc[b * 8 + e];
            if (s > v0) { v1 = v0; i1 = i0; v0 = s; i0 = e; }
            else if (s > v1) { v1 = s; i1 = e; }
        }
        // softmax(vals/2): 0.5*log2(e) = 0.7213475
        float t = __builtin_amdgcn_exp2f(0.7213475f * (v1 - v0));
        float den = __builtin_amdgcn_rcpf(1.0f + t);
        gidx[b * 2] = i0; gidx[b * 2 + 1] = i1;
        gw[b * 2] = den; gw[b * 2 + 1] = t * den;
    }
}

// ---------------------------------------------------------------------------
// Kernel 3: out = 0.5*(gelu(s0)+gelu(s1)) + w0*gelu(e[i0]) + w1*gelu(e[i1]).
// Wave w owns output channels [w*16, w*16+16) => per-wave A = 32 VGPRs only.
// Grid: 32 samples * 32 stripes of 512 px. Block 256 thr (4 waves).
// ---------------------------------------------------------------------------
__global__ __launch_bounds__(256, 4)
void k3_out(const bf16_t* __restrict__ feat, const bf16_t* __restrict__ wbf,
            const float* __restrict__ s_b, const float* __restrict__ e_b,
            const int* __restrict__ gidx, const float* __restrict__ gw,
            float* __restrict__ out) {
    int tid = threadIdx.x;
    int lane = tid & 63, wid = tid >> 6;
    int r16 = lane & 15, g = lane >> 4;
    int b = blockIdx.x >> 5;
    int stripe = blockIdx.x & 31;

    int i0 = gidx[2 * b], i1 = gidx[2 * b + 1];
    float coef[4] = {0.5f, 0.5f, gw[2 * b], gw[2 * b + 1]};
    int mats[4] = {1, 2, 3 + i0, 3 + i1};
    const float* Bm[4] = {s_b, s_b + 64, e_b + i0 * 64, e_b + i1 * 64};

    bf16x8 A[4][2];
    f32x4 biasr[4];
#pragma unroll
    for (int m = 0; m < 4; ++m) {
#pragma unroll
        for (int kh = 0; kh < 2; ++kh)
            A[m][kh] = *(const bf16x8*)(wbf + (size_t)((mats[m] * 4 + wid) * 2 + kh) * 512 + lane * 8);
#pragma unroll
        for (int r = 0; r < 4; ++r) biasr[m][r] = Bm[m][wid * 16 + g * 4 + r];
    }

    const uint4* fb = (const uint4*)(feat + (size_t)b * HW * 64);
    float* outb = out + (size_t)b * 64 * HW + (size_t)(wid * 16 + g * 4) * HW;
    int pbase = stripe * 512 + r16;

#pragma unroll 2
    for (int t = 0; t < 32; ++t) {
        int p = pbase + t * 16;
        uint4 u0 = fb[p * 8 + g];
        uint4 u1 = fb[p * 8 + 4 + g];
        bf16x8 B0 = __builtin_bit_cast(bf16x8, u0);
        bf16x8 B1 = __builtin_bit_cast(bf16x8, u1);
        f32x4 acc = {0.f, 0.f, 0.f, 0.f};
#pragma unroll
        for (int m = 0; m < 4; ++m) {
            f32x4 y = {0.f, 0.f, 0.f, 0.f};
            y = __builtin_amdgcn_mfma_f32_16x16x32_bf16(A[m][0], B0, y, 0, 0, 0);
            y = __builtin_amdgcn_mfma_f32_16x16x32_bf16(A[m][1], B1, y, 0, 0, 0);
#pragma unroll
            for (int r = 0; r < 4; ++r)
                acc[r] += coef[m] * gelu_f(y[r] + biasr[m][r]);
        }
#pragma unroll
        for (int r = 0; r < 4; ++r)
            outb[(size_t)r * HW + p] = acc[r];
    }
}

extern "C" void kernel_launch(void* const* d_in, const int* in_sizes, int n_in,
                              void* d_out, int out_size, void* d_ws, size_t ws_size,
                              hipStream_t stream) {
    const float* x     = (const float*)d_in[0];
    const float* fe_w  = (const float*)d_in[1];
    const float* fe_b  = (const float*)d_in[2];
    const float* s_w   = (const float*)d_in[3];
    const float* s_b   = (const float*)d_in[4];
    const float* e_w   = (const float*)d_in[5];
    const float* e_b   = (const float*)d_in[6];
    const float* g1_w  = (const float*)d_in[7];
    const float* g1_b  = (const float*)d_in[8];
    const float* bn1_g = (const float*)d_in[9];
    const float* bn1_b = (const float*)d_in[10];
    const float* ca1_w = (const float*)d_in[11];
    const float* ca1_b = (const float*)d_in[12];
    const float* ca2_w = (const float*)d_in[13];
    const float* ca2_b = (const float*)d_in[14];
    const float* g2_w  = (const float*)d_in[15];
    const float* g2_b  = (const float*)d_in[16];
    const float* bn2_g = (const float*)d_in[17];
    const float* bn2_b = (const float*)d_in[18];
    const float* g3_w  = (const float*)d_in[19];
    const float* g3_b  = (const float*)d_in[20];
    float* out = (float*)d_out;

    char* wsb = (char*)d_ws;
    bf16_t* feat  = (bf16_t*)wsb;                           // 64 MiB bf16 features
    float* gf_sum = (float*)(wsb + (size_t)67108864);       // 8 KiB
    int* gidx     = (int*)(wsb + 67108864 + 8192);          // 256 B
    float* gwts   = (float*)(wsb + 67108864 + 8192 + 256);  // 256 B
    bf16_t* wbf   = (bf16_t*)(wsb + 67125248);              // 90112 B bf16 weights

    hipMemsetAsync(gf_sum, 0, 32 * 64 * sizeof(float), stream);
    k0_conv<<<88, 64, 0, stream>>>(fe_w, s_w, e_w, wbf);
    k1_feat<<<2048, 256, 0, stream>>>(x, wbf, fe_b, feat, gf_sum);
    k2_gate<<<1, 256, 0, stream>>>(gf_sum, g1_w, g1_b, bn1_g, bn1_b, ca1_w, ca1_b,
                                   ca2_w, ca2_b, g2_w, g2_b, bn2_g, bn2_b, g3_w, g3_b,
                                   gidx, gwts);
    k3_out<<<1024, 256, 0, stream>>>(feat, wbf, s_b, e_b, gidx, gwts, out);
}

// Round 3
// 335.817 us; speedup vs baseline: 1.2957x; 1.1079x over previous
//
#include <hip/hip_runtime.h>
#include <hip/hip_bf16.h>
#include <stdint.h>

#define HW 16384
#define BATCH 32

typedef __bf16 bf16_t;
typedef bf16_t bf16x8 __attribute__((ext_vector_type(8)));
typedef float f32x4 __attribute__((ext_vector_type(4)));

// tanh-form GELU via hw exp2 + hw rcp:
// gelu(x) = x * sigmoid(1.5957691*(x + 0.044715 x^3)); 1.5957691*log2(e)=2.3022083
__device__ __forceinline__ float gelu_f(float x) {
    float t = x * fmaf(x * x, 0.044715f, 1.0f);
    float e = __builtin_amdgcn_exp2f(-2.3022083f * t);
    return x * __builtin_amdgcn_rcpf(1.0f + e);
}

__device__ __forceinline__ uint32_t pk2(float a, float b) {
    union { bf16_t h[2]; uint32_t u; } z;
    z.h[0] = (bf16_t)a; z.h[1] = (bf16_t)b;
    return z.u;
}

// async global->LDS, 16B per lane; LDS dest = uniform base + lane*16
__device__ __forceinline__ void load16_to_lds(const float* g, float* lds) {
    __builtin_amdgcn_global_load_lds(
        (const __attribute__((address_space(1))) uint32_t*)g,
        (__attribute__((address_space(3))) uint32_t*)lds, 16, 0, 0);
}

// ---------------------------------------------------------------------------
// Kernel 0: pre-convert weight matrices to bf16 in A-fragment lane order.
// m: 0=fe_w, 1..2=s_w, 3..10=e_w.
// ---------------------------------------------------------------------------
__global__ __launch_bounds__(64)
void k0_conv(const float* __restrict__ fe_w, const float* __restrict__ s_w,
             const float* __restrict__ e_w, bf16_t* __restrict__ wbf) {
    int blk = blockIdx.x;
    int m = blk >> 3;
    int ot = (blk >> 1) & 3;
    int kh = blk & 1;
    int lane = threadIdx.x;
    int r16 = lane & 15, g = lane >> 4;

    const float* W;
    if (m == 0) W = fe_w;
    else if (m <= 2) W = s_w + (size_t)(m - 1) * 4096;
    else W = e_w + (size_t)(m - 3) * 4096;

    const float* src = W + (ot * 16 + r16) * 64 + kh * 32 + g * 8;
    float4 lo = ((const float4*)src)[0];
    float4 hi = ((const float4*)src)[1];
    bf16x8 r;
    r[0] = (bf16_t)lo.x; r[1] = (bf16_t)lo.y; r[2] = (bf16_t)lo.z; r[3] = (bf16_t)lo.w;
    r[4] = (bf16_t)hi.x; r[5] = (bf16_t)hi.y; r[6] = (bf16_t)hi.z; r[7] = (bf16_t)hi.w;
    *(bf16x8*)(wbf + (size_t)blk * 512 + lane * 8) = r;
}

// ---------------------------------------------------------------------------
// Kernel 1: features = gelu(fe_w @ x + fe_b) -> bf16 pixel-major, + gf_sum.
// x staged fp32 to LDS via global_load_lds (width 16), with an XOR chunk
// swizzle on the GLOBAL side so strided B-frag reads are bank-conflict-free:
//   LDS row c (128 px, 512B) chunk j holds global px-chunk j ^ (4*gr),
//   gr = (c>>3)&3.  Reader window dword = c*128 + 16*(a^g) + r16.
// Grid: 32 samples * 128 stripes of 128 px. Block 256 thr (4 waves).
// ---------------------------------------------------------------------------
__global__ __launch_bounds__(256, 4)
void k1_feat(const float* __restrict__ x, const bf16_t* __restrict__ wbf,
             const float* __restrict__ fe_b, bf16_t* __restrict__ feat,
             float* __restrict__ gf_sum) {
    __shared__ float xs[64 * 128];     // 32 KB
    __shared__ float gf4[4][64];

    int tid = threadIdx.x;
    int lane = tid & 63;
    int wid = tid >> 6;
    int r16 = lane & 15;
    int g = lane >> 4;
    int b = blockIdx.x >> 7;
    int stripe = blockIdx.x & 127;
    int p0 = stripe * 128;

    // A fragments + bias
    bf16x8 A[4][2];
    f32x4 bias[4];
#pragma unroll
    for (int ot = 0; ot < 4; ++ot) {
#pragma unroll
        for (int kh = 0; kh < 2; ++kh)
            A[ot][kh] = *(const bf16x8*)(wbf + (size_t)(ot * 2 + kh) * 512 + lane * 8);
#pragma unroll
        for (int r = 0; r < 4; ++r) bias[ot][r] = fe_b[ot * 16 + g * 4 + r];
    }

    // DMA stage: wave wid stages rows [wid*16, wid*16+16), 2 rows per instr.
    {
        int rsub = lane >> 5;          // row within the pair
        int j = lane & 31;             // 16B chunk within row
#pragma unroll
        for (int s = 0; s < 8; ++s) {
            int c = wid * 16 + s * 2 + rsub;
            int gr = (c >> 3) & 3;
            const float* gsrc = x + (size_t)(b * 64 + c) * HW + p0 + ((j ^ (gr << 2)) << 2);
            float* ldst = xs + (wid * 16 + s * 2) * 128;   // uniform per instr
            load16_to_lds(gsrc, ldst);
        }
    }
    __syncthreads();

    float gfp[4][4] = {};
    bf16_t* featb = feat + (size_t)b * HW * 64;

#pragma unroll
    for (int t = 0; t < 2; ++t) {
        int a = wid * 2 + t;                    // 16-px window id, 0..7
        int wbase = 16 * (a ^ g) + r16;         // swizzled dword within row
        bf16x8 B0, B1;
#pragma unroll
        for (int j = 0; j < 8; ++j) {
            B0[j] = (bf16_t)xs[(g * 8 + j) * 128 + wbase];
            B1[j] = (bf16_t)xs[(32 + g * 8 + j) * 128 + wbase];
        }
        int pg = p0 + a * 16 + r16;
#pragma unroll
        for (int ot = 0; ot < 4; ++ot) {
            f32x4 y = {0.f, 0.f, 0.f, 0.f};
            y = __builtin_amdgcn_mfma_f32_16x16x32_bf16(A[ot][0], B0, y, 0, 0, 0);
            y = __builtin_amdgcn_mfma_f32_16x16x32_bf16(A[ot][1], B1, y, 0, 0, 0);
            float vr[4];
#pragma unroll
            for (int r = 0; r < 4; ++r) {
                float v = gelu_f(y[r] + bias[ot][r]);
                gfp[ot][r] += v;
                vr[r] = v;
            }
            uint2 st;
            st.x = pk2(vr[0], vr[1]);
            st.y = pk2(vr[2], vr[3]);
            *(uint2*)(featb + (size_t)pg * 64 + ot * 16 + g * 4) = st;
        }
    }

#pragma unroll
    for (int ot = 0; ot < 4; ++ot) {
#pragma unroll
        for (int r = 0; r < 4; ++r) {
            float v = gfp[ot][r];
            v += __shfl_xor(v, 1);
            v += __shfl_xor(v, 2);
            v += __shfl_xor(v, 4);
            v += __shfl_xor(v, 8);
            if (r16 == 0) gf4[wid][ot * 16 + g * 4 + r] = v;
        }
    }
    __syncthreads();
    if (tid < 64) {
        float s = gf4[0][tid] + gf4[1][tid] + gf4[2][tid] + gf4[3][tid];
        atomicAdd(gf_sum + b * 64 + tid, s);
    }
}

// ---------------------------------------------------------------------------
// Kernel 2: gating MLP. One block PER SAMPLE (grid=32). All weights staged
// to bank-padded LDS first (float4 loads), then pure-LDS compute.
// ---------------------------------------------------------------------------
__global__ __launch_bounds__(256)
void k2_gate(const float* __restrict__ gf_sum,
             const float* __restrict__ g1_w, const float* __restrict__ g1_b,
             const float* __restrict__ bn1_g, const float* __restrict__ bn1_b,
             const float* __restrict__ ca1_w, const float* __restrict__ ca1_b,
             const float* __restrict__ ca2_w, const float* __restrict__ ca2_b,
             const float* __restrict__ g2_w, const float* __restrict__ g2_b,
             const float* __restrict__ bn2_g, const float* __restrict__ bn2_b,
             const float* __restrict__ g3_w, const float* __restrict__ g3_b,
             int* __restrict__ gidx, float* __restrict__ gw) {
    __shared__ float w1t[128 * 65];    // g1_w padded
    __shared__ float wc1[8 * 129];     // ca1_w padded
    __shared__ float wc2[128 * 9];     // ca2_w padded
    __shared__ float w2t[64 * 129];    // g2_w padded
    __shared__ float w3[8 * 65];       // g3_w padded
    __shared__ float gf[64], h1[128], a1[8], hh[64], sc[8];
    const float R1 = 0.99999500003749969f;   // 1/sqrt(1+1e-5)
    int tid = threadIdx.x;
    int b = blockIdx.x;

    // stage weights: coalesced float4 global loads -> padded LDS rows
    for (int i = tid; i < 2048; i += 256) {        // g1_w [128][64]
        float4 v = ((const float4*)g1_w)[i];
        float* d = w1t + (i >> 4) * 65 + (i & 15) * 4;
        d[0] = v.x; d[1] = v.y; d[2] = v.z; d[3] = v.w;
    }
    for (int i = tid; i < 2048; i += 256) {        // g2_w [64][128]
        float4 v = ((const float4*)g2_w)[i];
        float* d = w2t + (i >> 5) * 129 + (i & 31) * 4;
        d[0] = v.x; d[1] = v.y; d[2] = v.z; d[3] = v.w;
    }
    if (tid < 256) {                               // ca1_w [8][128]
        int i = tid;
        float4 v = ((const float4*)ca1_w)[i];
        float* d = wc1 + (i >> 5) * 129 + (i & 31) * 4;
        d[0] = v.x; d[1] = v.y; d[2] = v.z; d[3] = v.w;
    }
    if (tid < 256) {                               // ca2_w [128][8]
        int i = tid;
        float4 v = ((const float4*)ca2_w)[i];
        float* d = wc2 + (i >> 1) * 9 + (i & 1) * 4;
        d[0] = v.x; d[1] = v.y; d[2] = v.z; d[3] = v.w;
    }
    if (tid < 128) {                               // g3_w [8][64]
        int i = tid;
        float4 v = ((const float4*)g3_w)[i];
        float* d = w3 + (i >> 4) * 65 + (i & 15) * 4;
        d[0] = v.x; d[1] = v.y; d[2] = v.z; d[3] = v.w;
    }
    if (tid < 64) gf[tid] = gf_sum[b * 64 + tid] * (1.0f / 16384.0f);
    __syncthreads();

    if (tid < 128) {                 // h1 = gelu(bn(g1))
        int j = tid;
        float s = g1_b[j];
#pragma unroll 8
        for (int c = 0; c < 64; ++c) s += gf[c] * w1t[j * 65 + c];
        s = s * (bn1_g[j] * R1) + bn1_b[j];
        h1[j] = gelu_f(s);
    }
    __syncthreads();
    if (tid < 8) {                   // a1 = gelu(ca1)
        int j = tid;
        float s = ca1_b[j];
#pragma unroll 8
        for (int c = 0; c < 128; ++c) s += h1[c] * wc1[j * 129 + c];
        a1[j] = gelu_f(s);
    }
    __syncthreads();
    if (tid < 128) {                 // h1 *= sigmoid(2*att)
        int j = tid;
        float s = ca2_b[j];
#pragma unroll
        for (int r = 0; r < 8; ++r) s += a1[r] * wc2[j * 9 + r];
        float e2 = __builtin_amdgcn_exp2f(-2.8853901f * s);  // 2*log2(e)
        h1[j] = h1[j] * __builtin_amdgcn_rcpf(1.0f + e2);
    }
    __syncthreads();
    if (tid < 64) {                  // hh = gelu(bn(g2))
        int j = tid;
        float s = g2_b[j];
#pragma unroll 8
        for (int c = 0; c < 128; ++c) s += h1[c] * w2t[j * 129 + c];
        s = s * (bn2_g[j] * R1) + bn2_b[j];
        hh[j] = gelu_f(s);
    }
    __syncthreads();
    if (tid < 8) {                   // scores
        int j = tid;
        float s = g3_b[j];
#pragma unroll 8
        for (int c = 0; c < 64; ++c) s += hh[c] * w3[j * 65 + c];
        sc[j] = s;
    }
    __syncthreads();
    if (tid == 0) {
        float v0 = -1e30f, v1 = -1e30f;
        int i0 = 0, i1 = 0;
#pragma unroll
        for (int e = 0; e < 8; ++e) {
            float s = sc[e];
            if (s > v0) { v1 = v0; i1 = i0; v0 = s; i0 = e; }
            else if (s > v1) { v1 = s; i1 = e; }
        }
        float t = __builtin_amdgcn_exp2f(0.7213475f * (v1 - v0));  // 0.5*log2(e)
        float den = __builtin_amdgcn_rcpf(1.0f + t);
        gidx[b * 2] = i0; gidx[b * 2 + 1] = i1;
        gw[b * 2] = den; gw[b * 2 + 1] = t * den;
    }
}

// ---------------------------------------------------------------------------
// Kernel 3: out = 0.5*(gelu(s0)+gelu(s1)) + w0*gelu(e[i0]) + w1*gelu(e[i1]).
// (unchanged from round 2)
// ---------------------------------------------------------------------------
__global__ __launch_bounds__(256, 4)
void k3_out(const bf16_t* __restrict__ feat, const bf16_t* __restrict__ wbf,
            const float* __restrict__ s_b, const float* __restrict__ e_b,
            const int* __restrict__ gidx, const float* __restrict__ gw,
            float* __restrict__ out) {
    int tid = threadIdx.x;
    int lane = tid & 63, wid = tid >> 6;
    int r16 = lane & 15, g = lane >> 4;
    int b = blockIdx.x >> 5;
    int stripe = blockIdx.x & 31;

    int i0 = gidx[2 * b], i1 = gidx[2 * b + 1];
    float coef[4] = {0.5f, 0.5f, gw[2 * b], gw[2 * b + 1]};
    int mats[4] = {1, 2, 3 + i0, 3 + i1};
    const float* Bm[4] = {s_b, s_b + 64, e_b + i0 * 64, e_b + i1 * 64};

    bf16x8 A[4][2];
    f32x4 biasr[4];
#pragma unroll
    for (int m = 0; m < 4; ++m) {
#pragma unroll
        for (int kh = 0; kh < 2; ++kh)
            A[m][kh] = *(const bf16x8*)(wbf + (size_t)((mats[m] * 4 + wid) * 2 + kh) * 512 + lane * 8);
#pragma unroll
        for (int r = 0; r < 4; ++r) biasr[m][r] = Bm[m][wid * 16 + g * 4 + r];
    }

    const uint4* fb = (const uint4*)(feat + (size_t)b * HW * 64);
    float* outb = out + (size_t)b * 64 * HW + (size_t)(wid * 16 + g * 4) * HW;
    int pbase = stripe * 512 + r16;

#pragma unroll 2
    for (int t = 0; t < 32; ++t) {
        int p = pbase + t * 16;
        uint4 u0 = fb[p * 8 + g];
        uint4 u1 = fb[p * 8 + 4 + g];
        bf16x8 B0 = __builtin_bit_cast(bf16x8, u0);
        bf16x8 B1 = __builtin_bit_cast(bf16x8, u1);
        f32x4 acc = {0.f, 0.f, 0.f, 0.f};
#pragma unroll
        for (int m = 0; m < 4; ++m) {
            f32x4 y = {0.f, 0.f, 0.f, 0.f};
            y = __builtin_amdgcn_mfma_f32_16x16x32_bf16(A[m][0], B0, y, 0, 0, 0);
            y = __builtin_amdgcn_mfma_f32_16x16x32_bf16(A[m][1], B1, y, 0, 0, 0);
#pragma unroll
            for (int r = 0; r < 4; ++r)
                acc[r] += coef[m] * gelu_f(y[r] + biasr[m][r]);
        }
#pragma unroll
        for (int r = 0; r < 4; ++r)
            outb[(size_t)r * HW + p] = acc[r];
    }
}

extern "C" void kernel_launch(void* const* d_in, const int* in_sizes, int n_in,
                              void* d_out, int out_size, void* d_ws, size_t ws_size,
                              hipStream_t stream) {
    const float* x     = (const float*)d_in[0];
    const float* fe_w  = (const float*)d_in[1];
    const float* fe_b  = (const float*)d_in[2];
    const float* s_w   = (const float*)d_in[3];
    const float* s_b   = (const float*)d_in[4];
    const float* e_w   = (const float*)d_in[5];
    const float* e_b   = (const float*)d_in[6];
    const float* g1_w  = (const float*)d_in[7];
    const float* g1_b  = (const float*)d_in[8];
    const float* bn1_g = (const float*)d_in[9];
    const float* bn1_b = (const float*)d_in[10];
    const float* ca1_w = (const float*)d_in[11];
    const float* ca1_b = (const float*)d_in[12];
    const float* ca2_w = (const float*)d_in[13];
    const float* ca2_b = (const float*)d_in[14];
    const float* g2_w  = (const float*)d_in[15];
    const float* g2_b  = (const float*)d_in[16];
    const float* bn2_g = (const float*)d_in[17];
    const float* bn2_b = (const float*)d_in[18];
    const float* g3_w  = (const float*)d_in[19];
    const float* g3_b  = (const float*)d_in[20];
    float* out = (float*)d_out;

    char* wsb = (char*)d_ws;
    bf16_t* feat  = (bf16_t*)wsb;                           // 64 MiB bf16 features
    float* gf_sum = (float*)(wsb + (size_t)67108864);       // 8 KiB
    int* gidx     = (int*)(wsb + 67108864 + 8192);          // 256 B
    float* gwts   = (float*)(wsb + 67108864 + 8192 + 256);  // 256 B
    bf16_t* wbf   = (bf16_t*)(wsb + 67125248);              // 90112 B bf16 weights

    hipMemsetAsync(gf_sum, 0, 32 * 64 * sizeof(float), stream);
    k0_conv<<<88, 64, 0, stream>>>(fe_w, s_w, e_w, wbf);
    k1_feat<<<4096, 256, 0, stream>>>(x, wbf, fe_b, feat, gf_sum);
    k2_gate<<<32, 256, 0, stream>>>(gf_sum, g1_w, g1_b, bn1_g, bn1_b, ca1_w, ca1_b,
                                    ca2_w, ca2_b, g2_w, g2_b, bn2_g, bn2_b, g3_w, g3_b,
                                    gidx, gwts);
    k3_out<<<1024, 256, 0, stream>>>(feat, wbf, s_b, e_b, gidx, gwts, out);
}